// Round 1
// baseline (593.014 us; speedup 1.0000x reference)
//
#include <hip/hip_runtime.h>

// GCNPredictor: 3-layer GCN (sum-aggregation) + sum-pool + MLP head, fp32.
// Inputs (setup_inputs order):
//  0 x[N,35] f32, 1 W_emb[35,8], 2 W_g0[8,128], 3 W_g1[128,128], 4 W_g2[128,128],
//  5 W_p1[128,64], 6 W_p2[64,1], 7 b_p2[1], 8 edge_src[E] i32, 9 edge_dst[E] i32,
//  10 graph_ids[N] i32 (sorted). Output: pred[2048] f32.

constexpr int NUM_GRAPHS = 2048;

// ---------------- h0 = x @ W_emb  ([N,35] @ [35,8]) ----------------
__global__ __launch_bounds__(256) void k_embed(const float* __restrict__ x,
                                               const float* __restrict__ Wemb,
                                               float* __restrict__ h0, int N) {
  __shared__ float sx[32 * 35];
  __shared__ float sw[35 * 8];
  int n0 = blockIdx.x * 32;
  int cnt = min(32, N - n0);
  int nf = cnt * 35;
  for (int i = threadIdx.x; i < nf; i += 256) sx[i] = x[(size_t)n0 * 35 + i];
  for (int i = threadIdx.x; i < 35 * 8; i += 256) sw[i] = Wemb[i];
  __syncthreads();
  int nl = threadIdx.x >> 3;  // node within block
  int c = threadIdx.x & 7;    // output channel
  if (nl < cnt) {
    float acc = 0.f;
#pragma unroll
    for (int k = 0; k < 35; ++k) acc = fmaf(sx[nl * 35 + k], sw[k * 8 + c], acc);
    h0[(size_t)(n0 + nl) * 8 + c] = acc;
  }
}

// ---------------- agg[dst] += h[src], d = 8 ----------------
__global__ __launch_bounds__(256) void k_scatter8(const float* __restrict__ h,
                                                  const int* __restrict__ src,
                                                  const int* __restrict__ dst,
                                                  float* agg, long long total) {
  long long t = (long long)blockIdx.x * 256 + threadIdx.x;
  long long stride = (long long)gridDim.x * 256;
  for (; t < total; t += stride) {
    int e = (int)(t >> 3);
    int f = (int)(t & 7);
    atomicAdd(&agg[(size_t)dst[e] * 8 + f], h[(size_t)src[e] * 8 + f]);
  }
}

// ---------------- agg[dst] += h[src], d = 128 ----------------
__global__ __launch_bounds__(256) void k_scatter128(const float* __restrict__ h,
                                                    const int* __restrict__ src,
                                                    const int* __restrict__ dst,
                                                    float* agg, long long total) {
  long long t = (long long)blockIdx.x * 256 + threadIdx.x;
  long long stride = (long long)gridDim.x * 256;
  for (; t < total; t += stride) {
    int e = (int)(t >> 7);
    int f = (int)(t & 127);
    atomicAdd(&agg[(size_t)dst[e] * 128 + f], h[(size_t)src[e] * 128 + f]);
  }
}

// ---------------- out = relu(A @ W_g0)  ([N,8] @ [8,128]) ----------------
__global__ __launch_bounds__(256) void k_gemm8(const float* __restrict__ A,
                                               const float* __restrict__ W,
                                               float* __restrict__ out, int N) {
  __shared__ float sw[8 * 128];
  for (int i = threadIdx.x; i < 8 * 128; i += 256) sw[i] = W[i];
  __syncthreads();
  int nl = threadIdx.x >> 5;          // 0..7  (node in block)
  int j0 = (threadIdx.x & 31) * 4;    // 0..124 (output col group)
  int n = blockIdx.x * 8 + nl;
  if (n >= N) return;
  float a[8];
#pragma unroll
  for (int k = 0; k < 8; ++k) a[k] = A[(size_t)n * 8 + k];
  float4 acc = {0.f, 0.f, 0.f, 0.f};
#pragma unroll
  for (int k = 0; k < 8; ++k) {
    float4 w = *reinterpret_cast<const float4*>(&sw[k * 128 + j0]);
    acc.x = fmaf(a[k], w.x, acc.x);
    acc.y = fmaf(a[k], w.y, acc.y);
    acc.z = fmaf(a[k], w.z, acc.z);
    acc.w = fmaf(a[k], w.w, acc.w);
  }
  acc.x = fmaxf(acc.x, 0.f);
  acc.y = fmaxf(acc.y, 0.f);
  acc.z = fmaxf(acc.z, 0.f);
  acc.w = fmaxf(acc.w, 0.f);
  *reinterpret_cast<float4*>(&out[(size_t)n * 128 + j0]) = acc;
}

// ---------------- out = relu(A @ W) + R  ([N,128] @ [128,128]) ----------------
// In-place safe (out may alias A): each block stages its 64 rows to LDS,
// barriers, then only writes its own rows.
__global__ __launch_bounds__(256) void k_gcn128(const float* A,
                                                const float* __restrict__ W,
                                                const float* __restrict__ R,
                                                float* out, int N) {
  __shared__ float sa[64 * 132];  // padded stride 132 -> conflict-free reads
  int n0 = blockIdx.x * 64;
  int cnt = min(64, N - n0);
  int tot = cnt * 128;
  for (int i = threadIdx.x; i < tot; i += 256)
    sa[(i >> 7) * 132 + (i & 127)] = A[(size_t)n0 * 128 + i];
  __syncthreads();
  int nl = threadIdx.x >> 4;        // 0..15
  int j0 = (threadIdx.x & 15) * 8;  // 0..120
  float acc[4][8];
#pragma unroll
  for (int r = 0; r < 4; ++r)
#pragma unroll
    for (int j = 0; j < 8; ++j) acc[r][j] = 0.f;
  const float* Wj = W + j0;
#pragma unroll 2
  for (int k = 0; k < 128; ++k) {
    float4 w0 = *reinterpret_cast<const float4*>(Wj + (size_t)k * 128);
    float4 w1 = *reinterpret_cast<const float4*>(Wj + (size_t)k * 128 + 4);
    float wv[8] = {w0.x, w0.y, w0.z, w0.w, w1.x, w1.y, w1.z, w1.w};
#pragma unroll
    for (int r = 0; r < 4; ++r) {
      float a = sa[(nl + 16 * r) * 132 + k];
#pragma unroll
      for (int j = 0; j < 8; ++j) acc[r][j] = fmaf(a, wv[j], acc[r][j]);
    }
  }
#pragma unroll
  for (int r = 0; r < 4; ++r) {
    int row = nl + 16 * r;
    if (row < cnt) {
      size_t base = (size_t)(n0 + row) * 128 + j0;
      float4 r0 = *reinterpret_cast<const float4*>(&R[base]);
      float4 r1 = *reinterpret_cast<const float4*>(&R[base + 4]);
      float4 o0, o1;
      o0.x = fmaxf(acc[r][0], 0.f) + r0.x;
      o0.y = fmaxf(acc[r][1], 0.f) + r0.y;
      o0.z = fmaxf(acc[r][2], 0.f) + r0.z;
      o0.w = fmaxf(acc[r][3], 0.f) + r0.w;
      o1.x = fmaxf(acc[r][4], 0.f) + r1.x;
      o1.y = fmaxf(acc[r][5], 0.f) + r1.y;
      o1.z = fmaxf(acc[r][6], 0.f) + r1.z;
      o1.w = fmaxf(acc[r][7], 0.f) + r1.w;
      *reinterpret_cast<float4*>(&out[base]) = o0;
      *reinterpret_cast<float4*>(&out[base + 4]) = o1;
    }
  }
}

// ---------------- g[gid[n]] += h[n]  (graph_ids sorted; run-length + atomic flush)
__global__ __launch_bounds__(128) void k_pool(const float* __restrict__ h,
                                              const int* __restrict__ gid,
                                              float* g, int N, int chunk) {
  int n0 = blockIdx.x * chunk;
  int n1 = min(N, n0 + chunk);
  if (n0 >= n1) return;
  int f = threadIdx.x;
  float acc = 0.f;
  int cur = gid[n0];
  for (int n = n0; n < n1; ++n) {
    int gg = gid[n];
    if (gg != cur) {
      atomicAdd(&g[(size_t)cur * 128 + f], acc);
      acc = 0.f;
      cur = gg;
    }
    acc += h[(size_t)n * 128 + f];
  }
  atomicAdd(&g[(size_t)cur * 128 + f], acc);
}

// ---------------- pred = relu(g @ W_p1) @ W_p2 + b ----------------
__global__ __launch_bounds__(64) void k_head(const float* __restrict__ g,
                                             const float* __restrict__ W1,
                                             const float* __restrict__ W2,
                                             const float* __restrict__ b,
                                             float* __restrict__ out) {
  int gi = blockIdx.x;
  int j = threadIdx.x;  // 0..63
  __shared__ float sg[128];
  sg[j] = g[(size_t)gi * 128 + j];
  sg[j + 64] = g[(size_t)gi * 128 + 64 + j];
  __syncthreads();
  float acc = 0.f;
#pragma unroll
  for (int k = 0; k < 128; ++k) acc = fmaf(sg[k], W1[k * 64 + j], acc);
  acc = fmaxf(acc, 0.f) * W2[j];
#pragma unroll
  for (int off = 32; off > 0; off >>= 1) acc += __shfl_down(acc, off);
  if (j == 0) out[gi] = acc + b[0];
}

extern "C" void kernel_launch(void* const* d_in, const int* in_sizes, int n_in,
                              void* d_out, int out_size, void* d_ws, size_t ws_size,
                              hipStream_t stream) {
  const float* x    = (const float*)d_in[0];
  const float* Wemb = (const float*)d_in[1];
  const float* Wg0  = (const float*)d_in[2];
  const float* Wg1  = (const float*)d_in[3];
  const float* Wg2  = (const float*)d_in[4];
  const float* Wp1  = (const float*)d_in[5];
  const float* Wp2  = (const float*)d_in[6];
  const float* bp2  = (const float*)d_in[7];
  const int* esrc   = (const int*)d_in[8];
  const int* edst   = (const int*)d_in[9];
  const int* gids   = (const int*)d_in[10];
  int N = in_sizes[0] / 35;
  int E = in_sizes[8];
  float* out = (float*)d_out;

  // workspace layout (floats)
  float* h0   = (float*)d_ws;            // N*8
  float* agg0 = h0 + (size_t)N * 8;      // N*8
  float* P    = agg0 + (size_t)N * 8;    // N*128
  float* Q    = P + (size_t)N * 128;     // N*128
  float* G    = Q + (size_t)N * 128;     // 2048*128

  // h0 = x @ W_emb
  k_embed<<<(N + 31) / 32, 256, 0, stream>>>(x, Wemb, h0, N);

  // layer 0: agg0 = scatter(h0); P = relu(agg0 @ W_g0)
  hipMemsetAsync(agg0, 0, (size_t)N * 8 * sizeof(float), stream);
  {
    long long total = (long long)E * 8;
    int blocks = (int)(((total + 255) / 256 < 4096) ? (total + 255) / 256 : 4096);
    k_scatter8<<<blocks, 256, 0, stream>>>(h0, esrc, edst, agg0, total);
  }
  k_gemm8<<<(N + 7) / 8, 256, 0, stream>>>(agg0, Wg0, P, N);

  // layer 1: Q = scatter(P); Q = relu(Q @ W_g1) + P   (in-place on Q)
  hipMemsetAsync(Q, 0, (size_t)N * 128 * sizeof(float), stream);
  {
    long long total = (long long)E * 128;
    k_scatter128<<<8192, 256, 0, stream>>>(P, esrc, edst, Q, total);
  }
  k_gcn128<<<(N + 63) / 64, 256, 0, stream>>>(Q, Wg1, P, Q, N);

  // layer 2: P = scatter(Q); P = relu(P @ W_g2) + Q   (in-place on P; h1 dead)
  hipMemsetAsync(P, 0, (size_t)N * 128 * sizeof(float), stream);
  {
    long long total = (long long)E * 128;
    k_scatter128<<<8192, 256, 0, stream>>>(Q, esrc, edst, P, total);
  }
  k_gcn128<<<(N + 63) / 64, 256, 0, stream>>>(P, Wg2, Q, P, N);

  // pool
  hipMemsetAsync(G, 0, (size_t)NUM_GRAPHS * 128 * sizeof(float), stream);
  int chunk = (N + 1023) / 1024;
  k_pool<<<1024, 128, 0, stream>>>(P, gids, G, N, chunk);

  // head
  k_head<<<NUM_GRAPHS, 64, 0, stream>>>(G, Wp1, Wp2, bp2, out);
}

// Round 2
// 577.970 us; speedup vs baseline: 1.0260x; 1.0260x over previous
//
#include <hip/hip_runtime.h>

// GCNPredictor: 3-layer GCN (sum-aggregation) + sum-pool + MLP head, fp32.
// Round 2: CSR-based gather aggregation (replaces atomic scatter), fused
// gather+GEMM+ReLU+residual per layer, pool fused into layer-2 epilogue.

constexpr int NUM_GRAPHS = 2048;

// ---------------- h0 = x @ W_emb  ([N,35] @ [35,8]) ----------------
__global__ __launch_bounds__(256) void k_embed(const float* __restrict__ x,
                                               const float* __restrict__ Wemb,
                                               float* __restrict__ h0, int N) {
  __shared__ float sx[32 * 35];
  __shared__ float sw[35 * 8];
  int n0 = blockIdx.x * 32;
  int cnt = min(32, N - n0);
  int nf = cnt * 35;
  for (int i = threadIdx.x; i < nf; i += 256) sx[i] = x[(size_t)n0 * 35 + i];
  for (int i = threadIdx.x; i < 35 * 8; i += 256) sw[i] = Wemb[i];
  __syncthreads();
  int nl = threadIdx.x >> 3;
  int c = threadIdx.x & 7;
  if (nl < cnt) {
    float acc = 0.f;
#pragma unroll
    for (int k = 0; k < 35; ++k) acc = fmaf(sx[nl * 35 + k], sw[k * 8 + c], acc);
    h0[(size_t)(n0 + nl) * 8 + c] = acc;
  }
}

// ---------------- CSR build: counts -> exclusive scan -> fill ----------------
__global__ __launch_bounds__(256) void k_hist(const int* __restrict__ dst,
                                              int* counts, int E) {
  int e = blockIdx.x * 256 + threadIdx.x;
  if (e < E) atomicAdd(&counts[dst[e]], 1);
}

__global__ __launch_bounds__(256) void k_scan1(const int* __restrict__ counts,
                                               int* __restrict__ offs,
                                               int* __restrict__ partials, int N) {
  __shared__ int s[256];
  int i = blockIdx.x * 256 + threadIdx.x;
  int v = (i < N) ? counts[i] : 0;
  s[threadIdx.x] = v;
  __syncthreads();
#pragma unroll
  for (int d = 1; d < 256; d <<= 1) {
    int t = (threadIdx.x >= d) ? s[threadIdx.x - d] : 0;
    __syncthreads();
    s[threadIdx.x] += t;
    __syncthreads();
  }
  if (i < N) offs[i] = s[threadIdx.x] - v;  // exclusive
  if (threadIdx.x == 255) partials[blockIdx.x] = s[255];
}

__global__ __launch_bounds__(512) void k_scan2(int* partials, int nb) {
  __shared__ int s[512];
  int t = threadIdx.x;
  int orig = (t < nb) ? partials[t] : 0;
  s[t] = orig;
  __syncthreads();
#pragma unroll
  for (int d = 1; d < 512; d <<= 1) {
    int v = (t >= d) ? s[t - d] : 0;
    __syncthreads();
    s[t] += v;
    __syncthreads();
  }
  if (t < nb) partials[t] = s[t] - orig;  // exclusive block offsets
}

__global__ __launch_bounds__(256) void k_scan3(int* __restrict__ offs,
                                               const int* __restrict__ partials,
                                               int* __restrict__ cursor, int N) {
  int i = blockIdx.x * 256 + threadIdx.x;
  if (i < N) {
    int v = offs[i] + partials[blockIdx.x];
    offs[i] = v;
    cursor[i] = v;
  }
}

__global__ __launch_bounds__(256) void k_fill(const int* __restrict__ src,
                                              const int* __restrict__ dst,
                                              int* cursor, int* __restrict__ csr,
                                              int E) {
  int e = blockIdx.x * 256 + threadIdx.x;
  if (e < E) {
    int slot = atomicAdd(&cursor[dst[e]], 1);
    csr[slot] = src[e];
  }
}

// -------- layer 0 fused: agg8 = gather(h0); out = relu(agg8 @ W_g0) --------
__global__ __launch_bounds__(256) void k_layer0(const float* __restrict__ h0,
                                                const int* __restrict__ csr,
                                                const int* __restrict__ offs,
                                                const int* __restrict__ cnts,
                                                const float* __restrict__ W,
                                                float* __restrict__ out, int N) {
  __shared__ float sagg[32 * 9];  // stride 9: conflict-free
  __shared__ float sw[8 * 128];
  for (int i = threadIdx.x; i < 1024; i += 256) sw[i] = W[i];
  int n0 = blockIdx.x * 32;
  {
    int i = threadIdx.x >> 3;
    int c = threadIdx.x & 7;
    int n = n0 + i;
    float acc = 0.f;
    if (n < N) {
      int s = offs[n], cc = cnts[n];
      for (int e = 0; e < cc; ++e) acc += h0[(size_t)csr[s + e] * 8 + c];
    }
    sagg[i * 9 + c] = acc;
  }
  __syncthreads();
  int i2 = threadIdx.x >> 3;
  int j0 = (threadIdx.x & 7) * 16;
  int n2 = n0 + i2;
  if (n2 >= N) return;
  float a[8];
#pragma unroll
  for (int k = 0; k < 8; ++k) a[k] = sagg[i2 * 9 + k];
  float o[16];
#pragma unroll
  for (int j = 0; j < 16; ++j) o[j] = 0.f;
#pragma unroll
  for (int k = 0; k < 8; ++k)
#pragma unroll
    for (int j = 0; j < 16; ++j) o[j] = fmaf(a[k], sw[k * 128 + j0 + j], o[j]);
  size_t base = (size_t)n2 * 128 + j0;
#pragma unroll
  for (int t = 0; t < 4; ++t) {
    float4 v;
    v.x = fmaxf(o[t * 4 + 0], 0.f);
    v.y = fmaxf(o[t * 4 + 1], 0.f);
    v.z = fmaxf(o[t * 4 + 2], 0.f);
    v.w = fmaxf(o[t * 4 + 3], 0.f);
    *reinterpret_cast<float4*>(&out[base + t * 4]) = v;
  }
}

// -------- fused GCN layer (d=128): agg = gather(H); v = relu(agg@W) + H --------
// mode 0: out[n] = v.   mode 1: G[gid[n]] += v (sum-pool fused, run-length in LDS).
__global__ __launch_bounds__(256) void k_gcn_fused(
    const float* __restrict__ H, const int* __restrict__ csr,
    const int* __restrict__ offs, const int* __restrict__ cnts,
    const float* __restrict__ W, float* __restrict__ out,
    float* G, const int* __restrict__ gid, int N, int mode) {
  __shared__ float sa[64 * 132];
  int n0 = blockIdx.x * 64;

  // gather phase: 2 groups of 128 threads, one column each
  {
    int grp = threadIdx.x >> 7;
    int j = threadIdx.x & 127;
    for (int i = grp; i < 64; i += 2) {
      int n = n0 + i;
      float acc = 0.f;
      if (n < N) {
        int s = offs[n], c = cnts[n];
        for (int e = 0; e < c; ++e)
          acc += H[(size_t)csr[s + e] * 128 + j];
      }
      sa[i * 132 + j] = acc;
    }
  }
  __syncthreads();

  // GEMM 64x128 @ 128x128
  int nl = threadIdx.x >> 4;
  int j0 = (threadIdx.x & 15) * 8;
  float acc[4][8];
#pragma unroll
  for (int r = 0; r < 4; ++r)
#pragma unroll
    for (int j = 0; j < 8; ++j) acc[r][j] = 0.f;
  const float* Wj = W + j0;
#pragma unroll 2
  for (int k = 0; k < 128; ++k) {
    float4 w0 = *reinterpret_cast<const float4*>(Wj + (size_t)k * 128);
    float4 w1 = *reinterpret_cast<const float4*>(Wj + (size_t)k * 128 + 4);
    float wv[8] = {w0.x, w0.y, w0.z, w0.w, w1.x, w1.y, w1.z, w1.w};
#pragma unroll
    for (int r = 0; r < 4; ++r) {
      float a = sa[(nl + 16 * r) * 132 + k];
#pragma unroll
      for (int j = 0; j < 8; ++j) acc[r][j] = fmaf(a, wv[j], acc[r][j]);
    }
  }

  if (mode == 0) {
#pragma unroll
    for (int r = 0; r < 4; ++r) {
      int row = nl + 16 * r;
      int n = n0 + row;
      if (n < N) {
        size_t base = (size_t)n * 128 + j0;
        float4 r0 = *reinterpret_cast<const float4*>(&H[base]);
        float4 r1 = *reinterpret_cast<const float4*>(&H[base + 4]);
        float4 o0, o1;
        o0.x = fmaxf(acc[r][0], 0.f) + r0.x;
        o0.y = fmaxf(acc[r][1], 0.f) + r0.y;
        o0.z = fmaxf(acc[r][2], 0.f) + r0.z;
        o0.w = fmaxf(acc[r][3], 0.f) + r0.w;
        o1.x = fmaxf(acc[r][4], 0.f) + r1.x;
        o1.y = fmaxf(acc[r][5], 0.f) + r1.y;
        o1.z = fmaxf(acc[r][6], 0.f) + r1.z;
        o1.w = fmaxf(acc[r][7], 0.f) + r1.w;
        *reinterpret_cast<float4*>(&out[base]) = o0;
        *reinterpret_cast<float4*>(&out[base + 4]) = o1;
      }
    }
  } else {
    // write v back into sa, then run-length pool into G
    __syncthreads();  // all GEMM reads of sa done
#pragma unroll
    for (int r = 0; r < 4; ++r) {
      int row = nl + 16 * r;
      int n = n0 + row;
      if (n < N) {
        size_t base = (size_t)n * 128 + j0;
        float4 r0 = *reinterpret_cast<const float4*>(&H[base]);
        float4 r1 = *reinterpret_cast<const float4*>(&H[base + 4]);
        float* srow = &sa[row * 132 + j0];
        srow[0] = fmaxf(acc[r][0], 0.f) + r0.x;
        srow[1] = fmaxf(acc[r][1], 0.f) + r0.y;
        srow[2] = fmaxf(acc[r][2], 0.f) + r0.z;
        srow[3] = fmaxf(acc[r][3], 0.f) + r0.w;
        srow[4] = fmaxf(acc[r][4], 0.f) + r1.x;
        srow[5] = fmaxf(acc[r][5], 0.f) + r1.y;
        srow[6] = fmaxf(acc[r][6], 0.f) + r1.z;
        srow[7] = fmaxf(acc[r][7], 0.f) + r1.w;
      }
    }
    __syncthreads();
    int grp = threadIdx.x >> 7;  // 0..1 -> rows [0,32) / [32,64)
    int j = threadIdx.x & 127;
    int r0 = grp * 32;
    int nfirst = n0 + r0;
    if (nfirst < N) {
      float pacc = 0.f;
      int cur = gid[nfirst];
      for (int r = r0; r < r0 + 32; ++r) {
        int n = n0 + r;
        if (n >= N) break;
        int g2 = gid[n];
        if (g2 != cur) {
          atomicAdd(&G[(size_t)cur * 128 + j], pacc);
          pacc = 0.f;
          cur = g2;
        }
        pacc += sa[r * 132 + j];
      }
      atomicAdd(&G[(size_t)cur * 128 + j], pacc);
    }
  }
}

// ---------------- pred = relu(g @ W_p1) @ W_p2 + b ----------------
__global__ __launch_bounds__(64) void k_head(const float* __restrict__ g,
                                             const float* __restrict__ W1,
                                             const float* __restrict__ W2,
                                             const float* __restrict__ b,
                                             float* __restrict__ out) {
  int gi = blockIdx.x;
  int j = threadIdx.x;
  __shared__ float sg[128];
  sg[j] = g[(size_t)gi * 128 + j];
  sg[j + 64] = g[(size_t)gi * 128 + 64 + j];
  __syncthreads();
  float acc = 0.f;
#pragma unroll
  for (int k = 0; k < 128; ++k) acc = fmaf(sg[k], W1[k * 64 + j], acc);
  acc = fmaxf(acc, 0.f) * W2[j];
#pragma unroll
  for (int off = 32; off > 0; off >>= 1) acc += __shfl_down(acc, off);
  if (j == 0) out[gi] = acc + b[0];
}

extern "C" void kernel_launch(void* const* d_in, const int* in_sizes, int n_in,
                              void* d_out, int out_size, void* d_ws, size_t ws_size,
                              hipStream_t stream) {
  const float* x    = (const float*)d_in[0];
  const float* Wemb = (const float*)d_in[1];
  const float* Wg0  = (const float*)d_in[2];
  const float* Wg1  = (const float*)d_in[3];
  const float* Wg2  = (const float*)d_in[4];
  const float* Wp1  = (const float*)d_in[5];
  const float* Wp2  = (const float*)d_in[6];
  const float* bp2  = (const float*)d_in[7];
  const int* esrc   = (const int*)d_in[8];
  const int* edst   = (const int*)d_in[9];
  const int* gids   = (const int*)d_in[10];
  int N = in_sizes[0] / 35;
  int E = in_sizes[8];
  float* out = (float*)d_out;

  // workspace layout
  float* h0 = (float*)d_ws;             // N*8
  float* P  = h0 + (size_t)N * 8;       // N*128
  float* Q  = P + (size_t)N * 128;      // N*128
  float* G  = Q + (size_t)N * 128;      // 2048*128
  int* counts   = (int*)(G + (size_t)NUM_GRAPHS * 128);  // N
  int* offs     = counts + N;                            // N
  int* cursor   = offs + N;                              // N
  int* partials = cursor + N;                            // 512
  int* csr      = partials + 512;                        // E

  int nbE = (E + 255) / 256;
  int nbN = (N + 255) / 256;

  // embed (independent)
  k_embed<<<(N + 31) / 32, 256, 0, stream>>>(x, Wemb, h0, N);

  // CSR build
  hipMemsetAsync(counts, 0, (size_t)N * sizeof(int), stream);
  k_hist<<<nbE, 256, 0, stream>>>(edst, counts, E);
  k_scan1<<<nbN, 256, 0, stream>>>(counts, offs, partials, N);
  k_scan2<<<1, 512, 0, stream>>>(partials, nbN);
  k_scan3<<<nbN, 256, 0, stream>>>(offs, partials, cursor, N);
  k_fill<<<nbE, 256, 0, stream>>>(esrc, edst, cursor, csr, E);

  // zero pooled output (layer-2 epilogue atomics accumulate into it)
  hipMemsetAsync(G, 0, (size_t)NUM_GRAPHS * 128 * sizeof(float), stream);

  // layer 0: P = relu(gather(h0) @ W_g0)
  k_layer0<<<(N + 31) / 32, 256, 0, stream>>>(h0, csr, offs, counts, Wg0, P, N);

  // layer 1: Q = relu(gather(P) @ W_g1) + P
  k_gcn_fused<<<(N + 63) / 64, 256, 0, stream>>>(P, csr, offs, counts, Wg1, Q,
                                                 nullptr, nullptr, N, 0);

  // layer 2 + pool: G[gid] += relu(gather(Q) @ W_g2) + Q
  k_gcn_fused<<<(N + 63) / 64, 256, 0, stream>>>(Q, csr, offs, counts, Wg2, nullptr,
                                                 G, gids, N, 1);

  // head
  k_head<<<NUM_GRAPHS, 64, 0, stream>>>(G, Wp1, Wp2, bp2, out);
}